// Round 3
// baseline (3748.566 us; speedup 1.0000x reference)
//
#include <hip/hip_runtime.h>
#include <hip/hip_bf16.h>

// TransformerShardA: 2-layer GPT-2 style shard. B=1, S=2048, D=768, H=12,
// hd=64, FFN=3072. Inputs f32 (+int idx), output f32 [1,2048,768].
//
// DTYPE FORENSICS (rounds 0-2): inputs/output are f32 (per the stub doc).
//   - Round 2 read f32 data as bf16 -> random 16-bit patterns -> NaN. QED f32 in.
//   - Round 1 wrote bf16 into the f32 d_out (half-filled buffer) -> err 5.29.
//   - The "3.796875 exactly bf16" from round 0 only shows the stored REF is
//     bf16-rounded for comparison (threshold = 2% of max|ref| = 0.0759).
//
// Round 3: round-1 f32 implementation, final GEMM writes f32 directly to d_out.
// Workspace layout (f32): x | h | qkv | o | ffa  (~63 MB)

#define SEQ 2048
#define DIM 768
#define NH 12
#define HD 64
#define FFN 3072
#define QKVD (3 * DIM)

// ---------------- embedding + positional ----------------
__global__ void embed_kernel(const int* __restrict__ idx,
                             const float* __restrict__ emb,
                             const float* __restrict__ pe,
                             float* __restrict__ x) {
    int i = blockIdx.x * 256 + threadIdx.x;   // i < SEQ*DIM
    int s = i / DIM;
    int d = i - s * DIM;
    x[i] = emb[idx[s] * DIM + d] + pe[i];
}

// ---------------- LayerNorm (one block per row) ----------------
__global__ void ln_kernel(const float* __restrict__ x,
                          const float* __restrict__ sc,
                          const float* __restrict__ bi,
                          float* __restrict__ h) {
    int row = blockIdx.x, tid = threadIdx.x;
    __shared__ float red[256];
    const float* xr = x + row * DIM;
    float v[3];
#pragma unroll
    for (int i = 0; i < 3; ++i) v[i] = xr[tid + i * 256];
    float s = v[0] + v[1] + v[2];
    red[tid] = s; __syncthreads();
    for (int t = 128; t > 0; t >>= 1) {
        if (tid < t) red[tid] += red[tid + t];
        __syncthreads();
    }
    float mean = red[0] * (1.0f / DIM);
    __syncthreads();
    float q = 0.f;
#pragma unroll
    for (int i = 0; i < 3; ++i) { float d = v[i] - mean; q += d * d; }
    red[tid] = q; __syncthreads();
    for (int t = 128; t > 0; t >>= 1) {
        if (tid < t) red[tid] += red[tid + t];
        __syncthreads();
    }
    float rstd = rsqrtf(red[0] * (1.0f / DIM) + 1e-5f);
#pragma unroll
    for (int i = 0; i < 3; ++i) {
        int d = tid + i * 256;
        h[row * DIM + d] = (v[i] - mean) * rstd * sc[d] + bi[d];
    }
}

// ---------------- tiled f32 GEMM: C = [res +] act(A@W + bias) ----------------
// A: [M,K] row-major, W: [K,N] row-major, bias: [N], res/C: [M,N]
// block: 256 threads, 64x64 tile, BK=16, 4x4 per thread.
template <bool GELU, bool RES>
__global__ void gemm_kernel(const float* __restrict__ A,
                            const float* __restrict__ W,
                            const float* __restrict__ bias,
                            const float* __restrict__ res,
                            float* __restrict__ C,
                            int M, int N, int K) {
    __shared__ float As[16][65];   // +1 pad: A-store is stride-64 otherwise
    __shared__ float Bs[16][64];
    int tid = threadIdx.x;
    int tx = tid & 15, ty = tid >> 4;
    int bm = blockIdx.y * 64, bn = blockIdx.x * 64;
    float acc[4][4] = {};
    for (int k0 = 0; k0 < K; k0 += 16) {
        {   // A tile 64x16, coalesced along k
            int kk = tid & 15, mbase = tid >> 4;
#pragma unroll
            for (int p = 0; p < 4; ++p) {
                int m = mbase + p * 16;
                As[kk][m] = A[(bm + m) * K + k0 + kk];
            }
        }
        {   // B tile 16x64, coalesced along n
            int n = tid & 63, kbase = tid >> 6;
#pragma unroll
            for (int p = 0; p < 4; ++p) {
                int kk = kbase + p * 4;
                Bs[kk][n] = W[(k0 + kk) * N + bn + n];
            }
        }
        __syncthreads();
#pragma unroll
        for (int kk = 0; kk < 16; ++kk) {
            float a[4], b[4];
#pragma unroll
            for (int i = 0; i < 4; ++i) a[i] = As[kk][ty * 4 + i];
#pragma unroll
            for (int j = 0; j < 4; ++j) b[j] = Bs[kk][tx * 4 + j];
#pragma unroll
            for (int i = 0; i < 4; ++i)
#pragma unroll
                for (int j = 0; j < 4; ++j)
                    acc[i][j] = fmaf(a[i], b[j], acc[i][j]);
        }
        __syncthreads();
    }
#pragma unroll
    for (int i = 0; i < 4; ++i) {
        int m = bm + ty * 4 + i;
#pragma unroll
        for (int j = 0; j < 4; ++j) {
            int n = bn + tx * 4 + j;
            float v = acc[i][j] + bias[n];
            if (GELU) v = 0.5f * v * (1.0f + erff(v * 0.70710678118654752f));
            if (RES) v += res[m * N + n];
            C[m * N + n] = v;
        }
    }
}

// ---------------- attention: one block per (query row, head) ----------------
// qkv: [SEQ, 3*DIM] with q at +0, k at +DIM, v at +2*DIM, each [NH, HD].
// o: [SEQ, DIM] with head-major inner layout (h*HD + d).
__global__ void attn_kernel(const float* __restrict__ qkv,
                            float* __restrict__ o) {
    int row = blockIdx.x, head = blockIdx.y;
    int tid = threadIdx.x;   // 256
    __shared__ float scb[SEQ];
    __shared__ float qs[HD];
    __shared__ float red[256];
    const float* qp = qkv + row * QKVD + head * HD;
    if (tid < HD) qs[tid] = qp[tid] * 0.125f;   // 1/sqrt(64)
    __syncthreads();
    // scores for j <= row
    float lmax = -1e30f;
    for (int j = tid; j <= row; j += 256) {
        const float* kp = qkv + j * QKVD + DIM + head * HD;
        float s = 0.f;
#pragma unroll
        for (int d = 0; d < HD; ++d) s = fmaf(qs[d], kp[d], s);
        scb[j] = s;
        lmax = fmaxf(lmax, s);
    }
    red[tid] = lmax; __syncthreads();
    for (int t = 128; t > 0; t >>= 1) {
        if (tid < t) red[tid] = fmaxf(red[tid], red[tid + t]);
        __syncthreads();
    }
    float m = red[0];
    __syncthreads();
    float lsum = 0.f;
    for (int j = tid; j <= row; j += 256) {
        float p = expf(scb[j] - m);
        scb[j] = p;
        lsum += p;
    }
    red[tid] = lsum; __syncthreads();
    for (int t = 128; t > 0; t >>= 1) {
        if (tid < t) red[tid] += red[tid + t];
        __syncthreads();
    }
    float inv = 1.0f / red[0];
    __syncthreads();
    // PV: thread t -> dim d = t&63, key group g = t>>6 (4 groups)
    int d = tid & 63, g = tid >> 6;
    float acc = 0.f;
    for (int j = g; j <= row; j += 4)
        acc = fmaf(scb[j], qkv[j * QKVD + 2 * DIM + head * HD + d], acc);
    red[tid] = acc; __syncthreads();
    if (tid < 64) {
        float t = red[tid] + red[tid + 64] + red[tid + 128] + red[tid + 192];
        o[row * DIM + head * HD + tid] = t * inv;
    }
}

extern "C" void kernel_launch(void* const* d_in, const int* in_sizes, int n_in,
                              void* d_out, int out_size, void* d_ws, size_t ws_size,
                              hipStream_t stream) {
    const int*   idx     = (const int*)  d_in[0];
    const float* emb     = (const float*)d_in[1];
    const float* pe      = (const float*)d_in[2];
    const float* qkv_w   = (const float*)d_in[3];
    const float* qkv_b   = (const float*)d_in[4];
    const float* out_w   = (const float*)d_in[5];
    const float* out_b   = (const float*)d_in[6];
    const float* ln1_s   = (const float*)d_in[7];
    const float* ln1_b   = (const float*)d_in[8];
    const float* ln2_s   = (const float*)d_in[9];
    const float* ln2_b   = (const float*)d_in[10];
    const float* w1      = (const float*)d_in[11];
    const float* b1      = (const float*)d_in[12];
    const float* w2      = (const float*)d_in[13];
    const float* b2      = (const float*)d_in[14];

    float* x   = (float*)d_ws;
    float* h   = x   + SEQ * DIM;
    float* qkv = h   + SEQ * DIM;
    float* o   = qkv + SEQ * QKVD;
    float* ffa = o   + SEQ * DIM;

    embed_kernel<<<SEQ * DIM / 256, 256, 0, stream>>>(idx, emb, pe, x);

    for (int l = 0; l < 2; ++l) {
        ln_kernel<<<SEQ, 256, 0, stream>>>(x, ln1_s + l * DIM, ln1_b + l * DIM, h);
        gemm_kernel<false, false><<<dim3(QKVD / 64, SEQ / 64), 256, 0, stream>>>(
            h, qkv_w + (size_t)l * DIM * QKVD, qkv_b + l * QKVD, nullptr, qkv,
            SEQ, QKVD, DIM);
        attn_kernel<<<dim3(SEQ, NH), 256, 0, stream>>>(qkv, o);
        gemm_kernel<false, true><<<dim3(DIM / 64, SEQ / 64), 256, 0, stream>>>(
            o, out_w + (size_t)l * DIM * DIM, out_b + l * DIM, x, x,
            SEQ, DIM, DIM);
        ln_kernel<<<SEQ, 256, 0, stream>>>(x, ln2_s + l * DIM, ln2_b + l * DIM, h);
        gemm_kernel<true, false><<<dim3(FFN / 64, SEQ / 64), 256, 0, stream>>>(
            h, w1 + (size_t)l * DIM * FFN, b1 + l * FFN, nullptr, ffa,
            SEQ, FFN, DIM);
        // Last GEMM of layer 1 writes the final residual x directly to d_out (f32).
        float* cdst = (l == 1) ? (float*)d_out : x;
        gemm_kernel<false, true><<<dim3(DIM / 64, SEQ / 64), 256, 0, stream>>>(
            ffa, w2 + (size_t)l * FFN * DIM, b2 + l * DIM, x, cdst,
            SEQ, DIM, FFN);
    }
}

// Round 4
// 2091.242 us; speedup vs baseline: 1.7925x; 1.7925x over previous
//
#include <hip/hip_runtime.h>
#include <hip/hip_bf16.h>

// TransformerShardA: 2-layer GPT-2 style shard. B=1, S=2048, D=768, H=12,
// hd=64, FFN=3072. Inputs f32 (+int idx), output f32 [1,2048,768].
//
// Round 4: flash-style tiled attention (the 2x1280us hotspot).
//   - block = (head, 64-row Q tile); K/V staged in LDS 64-key tiles
//   - online softmax, 4x4 register tiles, b128 LDS reads, XOR swizzle
// GEMMs unchanged from round 3 (next target: bf16 MFMA).

#define SEQ 2048
#define DIM 768
#define NH 12
#define HD 64
#define FFN 3072
#define QKVD (3 * DIM)

// ---------------- embedding + positional ----------------
__global__ void embed_kernel(const int* __restrict__ idx,
                             const float* __restrict__ emb,
                             const float* __restrict__ pe,
                             float* __restrict__ x) {
    int i = blockIdx.x * 256 + threadIdx.x;
    int s = i / DIM;
    int d = i - s * DIM;
    x[i] = emb[idx[s] * DIM + d] + pe[i];
}

// ---------------- LayerNorm (one block per row) ----------------
__global__ void ln_kernel(const float* __restrict__ x,
                          const float* __restrict__ sc,
                          const float* __restrict__ bi,
                          float* __restrict__ h) {
    int row = blockIdx.x, tid = threadIdx.x;
    __shared__ float red[256];
    const float* xr = x + row * DIM;
    float v[3];
#pragma unroll
    for (int i = 0; i < 3; ++i) v[i] = xr[tid + i * 256];
    float s = v[0] + v[1] + v[2];
    red[tid] = s; __syncthreads();
    for (int t = 128; t > 0; t >>= 1) {
        if (tid < t) red[tid] += red[tid + t];
        __syncthreads();
    }
    float mean = red[0] * (1.0f / DIM);
    __syncthreads();
    float q = 0.f;
#pragma unroll
    for (int i = 0; i < 3; ++i) { float d = v[i] - mean; q += d * d; }
    red[tid] = q; __syncthreads();
    for (int t = 128; t > 0; t >>= 1) {
        if (tid < t) red[tid] += red[tid + t];
        __syncthreads();
    }
    float rstd = rsqrtf(red[0] * (1.0f / DIM) + 1e-5f);
#pragma unroll
    for (int i = 0; i < 3; ++i) {
        int d = tid + i * 256;
        h[row * DIM + d] = (v[i] - mean) * rstd * sc[d] + bi[d];
    }
}

// ---------------- tiled f32 GEMM: C = [res +] act(A@W + bias) ----------------
template <bool GELU, bool RES>
__global__ void gemm_kernel(const float* __restrict__ A,
                            const float* __restrict__ W,
                            const float* __restrict__ bias,
                            const float* __restrict__ res,
                            float* __restrict__ C,
                            int M, int N, int K) {
    __shared__ float As[16][65];
    __shared__ float Bs[16][64];
    int tid = threadIdx.x;
    int tx = tid & 15, ty = tid >> 4;
    int bm = blockIdx.y * 64, bn = blockIdx.x * 64;
    float acc[4][4] = {};
    for (int k0 = 0; k0 < K; k0 += 16) {
        {
            int kk = tid & 15, mbase = tid >> 4;
#pragma unroll
            for (int p = 0; p < 4; ++p) {
                int m = mbase + p * 16;
                As[kk][m] = A[(bm + m) * K + k0 + kk];
            }
        }
        {
            int n = tid & 63, kbase = tid >> 6;
#pragma unroll
            for (int p = 0; p < 4; ++p) {
                int kk = kbase + p * 4;
                Bs[kk][n] = W[(k0 + kk) * N + bn + n];
            }
        }
        __syncthreads();
#pragma unroll
        for (int kk = 0; kk < 16; ++kk) {
            float a[4], b[4];
#pragma unroll
            for (int i = 0; i < 4; ++i) a[i] = As[kk][ty * 4 + i];
#pragma unroll
            for (int j = 0; j < 4; ++j) b[j] = Bs[kk][tx * 4 + j];
#pragma unroll
            for (int i = 0; i < 4; ++i)
#pragma unroll
                for (int j = 0; j < 4; ++j)
                    acc[i][j] = fmaf(a[i], b[j], acc[i][j]);
        }
        __syncthreads();
    }
#pragma unroll
    for (int i = 0; i < 4; ++i) {
        int m = bm + ty * 4 + i;
#pragma unroll
        for (int j = 0; j < 4; ++j) {
            int n = bn + tx * 4 + j;
            float v = acc[i][j] + bias[n];
            if (GELU) v = 0.5f * v * (1.0f + erff(v * 0.70710678118654752f));
            if (RES) v += res[m * N + n];
            C[m * N + n] = v;
        }
    }
}

// ---------------- flash attention ----------------
// qkv: [SEQ, 3*DIM], q at +0, k at +DIM, v at +2*DIM, inner [NH, HD].
// o: [SEQ, DIM] head-major (h*HD + d).
// Block 256 thr = 16 row-groups(tq) x 16 (tk in scores / td in PV).
// LDS float4 arrays swizzled: chunk c4 of row r stored at col 4*(c4^((r>>2)&7)).

__device__ __forceinline__ float4 lds_r4(const float* buf, int r, int c4) {
    return *(const float4*)&buf[r * 64 + 4 * (c4 ^ ((r >> 2) & 7))];
}
__device__ __forceinline__ void lds_w4(float* buf, int r, int c4, float4 v) {
    *(float4*)&buf[r * 64 + 4 * (c4 ^ ((r >> 2) & 7))] = v;
}

__global__ __launch_bounds__(256) void flash_attn_kernel(
        const float* __restrict__ qkv, float* __restrict__ o) {
    int qt = gridDim.x - 1 - blockIdx.x;   // heavy tiles first
    int head = blockIdx.y;
    int tid = threadIdx.x;
    int tq = tid >> 4;          // 0..15  (owns rows 4*tq..4*tq+3)
    int tk = tid & 15;          // scores: keys 4*tk..+3 ; PV: dim chunk td

    __shared__ float Qs[64 * 64];
    __shared__ float Ks[64 * 64];
    __shared__ float Vs[64 * 64];
    __shared__ float Ps[64 * 68];   // stride 68 floats (16B-aligned rows)

    // stage Q tile (scaled by 1/sqrt(64)=0.125)
    {
        int r = tid >> 2, cb = (tid & 3) * 4;
        const float* qp = qkv + (size_t)(qt * 64 + r) * QKVD + head * HD;
#pragma unroll
        for (int m = 0; m < 4; ++m) {
            float4 v = *(const float4*)&qp[(cb + m) * 4];
            v.x *= 0.125f; v.y *= 0.125f; v.z *= 0.125f; v.w *= 0.125f;
            lds_w4(Qs, r, cb + m, v);
        }
    }

    float m_i[4], l_i[4], o_acc[4][4];
#pragma unroll
    for (int i = 0; i < 4; ++i) {
        m_i[i] = -1e30f; l_i[i] = 0.f;
#pragma unroll
        for (int j = 0; j < 4; ++j) o_acc[i][j] = 0.f;
    }

    for (int kt = 0; kt <= qt; ++kt) {
        // ---- stage K,V tile ----
        {
            int r = tid >> 2, cb = (tid & 3) * 4;
            const float* kp = qkv + (size_t)(kt * 64 + r) * QKVD + DIM + head * HD;
            const float* vp = kp + DIM;
#pragma unroll
            for (int m = 0; m < 4; ++m)
                lds_w4(Ks, r, cb + m, *(const float4*)&kp[(cb + m) * 4]);
#pragma unroll
            for (int m = 0; m < 4; ++m)
                lds_w4(Vs, r, cb + m, *(const float4*)&vp[(cb + m) * 4]);
        }
        __syncthreads();

        // ---- scores: S[4q][4k] = Q.K^T ----
        float acc[4][4] = {};
#pragma unroll 4
        for (int c4 = 0; c4 < 16; ++c4) {
            float4 qv[4], kv[4];
#pragma unroll
            for (int i = 0; i < 4; ++i) qv[i] = lds_r4(Qs, 4 * tq + i, c4);
#pragma unroll
            for (int j = 0; j < 4; ++j) kv[j] = lds_r4(Ks, 4 * tk + j, c4);
#pragma unroll
            for (int i = 0; i < 4; ++i)
#pragma unroll
                for (int j = 0; j < 4; ++j)
                    acc[i][j] += qv[i].x * kv[j].x + qv[i].y * kv[j].y +
                                 qv[i].z * kv[j].z + qv[i].w * kv[j].w;
        }
        // causal mask on diagonal tile
        if (kt == qt) {
#pragma unroll
            for (int i = 0; i < 4; ++i)
#pragma unroll
                for (int j = 0; j < 4; ++j)
                    if (4 * tk + j > 4 * tq + i) acc[i][j] = -1e30f;
        }

        // ---- online softmax (row group = 16 contiguous lanes) ----
#pragma unroll
        for (int i = 0; i < 4; ++i) {
            float tmax = fmaxf(fmaxf(acc[i][0], acc[i][1]),
                               fmaxf(acc[i][2], acc[i][3]));
            tmax = fmaxf(tmax, __shfl_xor(tmax, 1));
            tmax = fmaxf(tmax, __shfl_xor(tmax, 2));
            tmax = fmaxf(tmax, __shfl_xor(tmax, 4));
            tmax = fmaxf(tmax, __shfl_xor(tmax, 8));
            float m_new = fmaxf(m_i[i], tmax);
            float alpha = __expf(m_i[i] - m_new);
            m_i[i] = m_new;
            float p0 = __expf(acc[i][0] - m_new);
            float p1 = __expf(acc[i][1] - m_new);
            float p2 = __expf(acc[i][2] - m_new);
            float p3 = __expf(acc[i][3] - m_new);
            float ts = p0 + p1 + p2 + p3;
            ts += __shfl_xor(ts, 1);
            ts += __shfl_xor(ts, 2);
            ts += __shfl_xor(ts, 4);
            ts += __shfl_xor(ts, 8);
            l_i[i] = l_i[i] * alpha + ts;
            float* pr = &Ps[(4 * tq + i) * 68 + 4 * tk];
            pr[0] = p0; pr[1] = p1; pr[2] = p2; pr[3] = p3;
#pragma unroll
            for (int j = 0; j < 4; ++j) o_acc[i][j] *= alpha;
        }
        __syncthreads();

        // ---- PV: O[4q][4d] += P.V  (td = tk reused as dim chunk) ----
#pragma unroll 4
        for (int kk4 = 0; kk4 < 16; ++kk4) {
            float4 pv[4];
#pragma unroll
            for (int i = 0; i < 4; ++i)
                pv[i] = *(const float4*)&Ps[(4 * tq + i) * 68 + kk4 * 4];
#pragma unroll
            for (int jj = 0; jj < 4; ++jj) {
                float4 vv = lds_r4(Vs, kk4 * 4 + jj, tk);
                float pj[4] = {pv[0].x, pv[1].x, pv[2].x, pv[3].x};
                if (jj == 1) { pj[0] = pv[0].y; pj[1] = pv[1].y; pj[2] = pv[2].y; pj[3] = pv[3].y; }
                if (jj == 2) { pj[0] = pv[0].z; pj[1] = pv[1].z; pj[2] = pv[2].z; pj[3] = pv[3].z; }
                if (jj == 3) { pj[0] = pv[0].w; pj[1] = pv[1].w; pj[2] = pv[2].w; pj[3] = pv[3].w; }
#pragma unroll
                for (int i = 0; i < 4; ++i) {
                    o_acc[i][0] = fmaf(pj[i], vv.x, o_acc[i][0]);
                    o_acc[i][1] = fmaf(pj[i], vv.y, o_acc[i][1]);
                    o_acc[i][2] = fmaf(pj[i], vv.z, o_acc[i][2]);
                    o_acc[i][3] = fmaf(pj[i], vv.w, o_acc[i][3]);
                }
            }
        }
        __syncthreads();
    }

    // ---- epilogue ----
#pragma unroll
    for (int i = 0; i < 4; ++i) {
        float inv = 1.0f / l_i[i];
        int row = qt * 64 + 4 * tq + i;
        float4 r;
        r.x = o_acc[i][0] * inv; r.y = o_acc[i][1] * inv;
        r.z = o_acc[i][2] * inv; r.w = o_acc[i][3] * inv;
        *(float4*)&o[(size_t)row * DIM + head * HD + tk * 4] = r;
    }
}

extern "C" void kernel_launch(void* const* d_in, const int* in_sizes, int n_in,
                              void* d_out, int out_size, void* d_ws, size_t ws_size,
                              hipStream_t stream) {
    const int*   idx     = (const int*)  d_in[0];
    const float* emb     = (const float*)d_in[1];
    const float* pe      = (const float*)d_in[2];
    const float* qkv_w   = (const float*)d_in[3];
    const float* qkv_b   = (const float*)d_in[4];
    const float* out_w   = (const float*)d_in[5];
    const float* out_b   = (const float*)d_in[6];
    const float* ln1_s   = (const float*)d_in[7];
    const float* ln1_b   = (const float*)d_in[8];
    const float* ln2_s   = (const float*)d_in[9];
    const float* ln2_b   = (const float*)d_in[10];
    const float* w1      = (const float*)d_in[11];
    const float* b1      = (const float*)d_in[12];
    const float* w2      = (const float*)d_in[13];
    const float* b2      = (const float*)d_in[14];

    float* x   = (float*)d_ws;
    float* h   = x   + SEQ * DIM;
    float* qkv = h   + SEQ * DIM;
    float* o   = qkv + SEQ * QKVD;
    float* ffa = o   + SEQ * DIM;

    embed_kernel<<<SEQ * DIM / 256, 256, 0, stream>>>(idx, emb, pe, x);

    for (int l = 0; l < 2; ++l) {
        ln_kernel<<<SEQ, 256, 0, stream>>>(x, ln1_s + l * DIM, ln1_b + l * DIM, h);
        gemm_kernel<false, false><<<dim3(QKVD / 64, SEQ / 64), 256, 0, stream>>>(
            h, qkv_w + (size_t)l * DIM * QKVD, qkv_b + l * QKVD, nullptr, qkv,
            SEQ, QKVD, DIM);
        flash_attn_kernel<<<dim3(SEQ / 64, NH), 256, 0, stream>>>(qkv, o);
        gemm_kernel<false, true><<<dim3(DIM / 64, SEQ / 64), 256, 0, stream>>>(
            o, out_w + (size_t)l * DIM * DIM, out_b + l * DIM, x, x,
            SEQ, DIM, DIM);
        ln_kernel<<<SEQ, 256, 0, stream>>>(x, ln2_s + l * DIM, ln2_b + l * DIM, h);
        gemm_kernel<true, false><<<dim3(FFN / 64, SEQ / 64), 256, 0, stream>>>(
            h, w1 + (size_t)l * DIM * FFN, b1 + l * FFN, nullptr, ffa,
            SEQ, FFN, DIM);
        float* cdst = (l == 1) ? (float*)d_out : x;
        gemm_kernel<false, true><<<dim3(DIM / 64, SEQ / 64), 256, 0, stream>>>(
            ffa, w2 + (size_t)l * FFN * DIM, b2 + l * DIM, x, cdst,
            SEQ, DIM, FFN);
    }
}

// Round 5
// 1118.580 us; speedup vs baseline: 3.3512x; 1.8695x over previous
//
#include <hip/hip_runtime.h>
#include <hip/hip_bf16.h>

// TransformerShardA: 2-layer GPT-2 shard. B=1, S=2048, D=768, H=12, hd=64,
// FFN=3072. Inputs f32 (+int idx), output f32 [1,2048,768].
//
// Round 5:
//  - bf16 MFMA GEMMs (16x16x32, 128x128 tile, BK=32, 4 waves x 4x4 frags).
//    Weights transposed->bf16 [N,K] into d_ws per call; activations bf16.
//  - flash attention: 32-row Q tiles (LDS 49.4KB -> 3 blocks/CU, 768 blocks),
//    bf16 Q/K/V loads. Residual stream x stays f32.
// WS (59.8 MB): x f32 | h bf16 (=o) | qkv bf16 | ffa bf16 | wT bf16

#define SEQ 2048
#define DIM 768
#define NH 12
#define HD 64
#define FFN 3072
#define QKVD (3 * DIM)

typedef __attribute__((ext_vector_type(8))) short short8;
typedef __attribute__((ext_vector_type(4))) float f32x4;

// ---------------- embedding + positional ----------------
__global__ void embed_kernel(const int* __restrict__ idx,
                             const float* __restrict__ emb,
                             const float* __restrict__ pe,
                             float* __restrict__ x) {
    int i = blockIdx.x * 256 + threadIdx.x;
    int s = i / DIM;
    int d = i - s * DIM;
    x[i] = emb[idx[s] * DIM + d] + pe[i];
}

// ---------------- weight transpose + cast: W[K,N] f32 -> WT[N,K] bf16 -------
__global__ void transpose_w(const float* __restrict__ W,
                            __hip_bfloat16* __restrict__ WT, int K, int N) {
    __shared__ float t[32][33];
    const float* Wp = W + (size_t)blockIdx.z * K * N;
    __hip_bfloat16* Tp = WT + (size_t)blockIdx.z * K * N;
    int k0 = blockIdx.y * 32, n0 = blockIdx.x * 32;
    int r = threadIdx.x >> 3, c4 = (threadIdx.x & 7) * 4;
    float4 v = *(const float4*)&Wp[(size_t)(k0 + r) * N + n0 + c4];
    t[r][c4 + 0] = v.x; t[r][c4 + 1] = v.y; t[r][c4 + 2] = v.z; t[r][c4 + 3] = v.w;
    __syncthreads();
    __hip_bfloat16* dst = &Tp[(size_t)(n0 + r) * K + k0 + c4];
#pragma unroll
    for (int j = 0; j < 4; ++j) dst[j] = __float2bfloat16(t[c4 + j][r]);
}

// ---------------- LayerNorm (one block per row), writes bf16 ----------------
__global__ void ln_kernel(const float* __restrict__ x,
                          const float* __restrict__ sc,
                          const float* __restrict__ bi,
                          __hip_bfloat16* __restrict__ h) {
    int row = blockIdx.x, tid = threadIdx.x;
    __shared__ float red[256];
    const float* xr = x + row * DIM;
    float v[3];
#pragma unroll
    for (int i = 0; i < 3; ++i) v[i] = xr[tid + i * 256];
    float s = v[0] + v[1] + v[2];
    red[tid] = s; __syncthreads();
    for (int t = 128; t > 0; t >>= 1) {
        if (tid < t) red[tid] += red[tid + t];
        __syncthreads();
    }
    float mean = red[0] * (1.0f / DIM);
    __syncthreads();
    float q = 0.f;
#pragma unroll
    for (int i = 0; i < 3; ++i) { float d = v[i] - mean; q += d * d; }
    red[tid] = q; __syncthreads();
    for (int t = 128; t > 0; t >>= 1) {
        if (tid < t) red[tid] += red[tid + t];
        __syncthreads();
    }
    float rstd = rsqrtf(red[0] * (1.0f / DIM) + 1e-5f);
#pragma unroll
    for (int i = 0; i < 3; ++i) {
        int d = tid + i * 256;
        h[row * DIM + d] = __float2bfloat16((v[i] - mean) * rstd * sc[d] + bi[d]);
    }
}

// ---------------- bf16 MFMA GEMM: C = [res +] act(A@W + bias) ---------------
// A: [M,K] bf16 row-major. WT: [N,K] bf16 (W transposed). bias f32 [N].
// res f32 [M,N] or null. Cout f32 or bf16 [M,N].
// 256 thr = 4 waves in 2x2; tile 128x128, BK=32; per wave 4x4 MFMA frags.
// Layouts (verified m89/m91/m120): A-frag A[m=lane&15][k=quad*8+j];
// C/D col=lane&15, row=quad*4+reg.
template <bool GELU, bool RES, bool OUTBF16>
__global__ __launch_bounds__(256) void mfma_gemm(
        const ushort* __restrict__ A, const ushort* __restrict__ WT,
        const float* __restrict__ bias, const float* __restrict__ res,
        void* __restrict__ Cout, int M, int N, int K) {
    __shared__ ushort As[128 * 32];
    __shared__ ushort Bs[128 * 32];
    int tid = threadIdx.x;
    int w = tid >> 6, lane = tid & 63;
    int wm = (w >> 1) * 64, wn = (w & 1) * 64;
    int bm = blockIdx.y * 128, bn = blockIdx.x * 128;
    int lm = lane & 15, q8 = (lane >> 4) * 8;

    f32x4 acc[4][4];
#pragma unroll
    for (int i = 0; i < 4; ++i)
#pragma unroll
        for (int j = 0; j < 4; ++j) acc[i][j] = {0.f, 0.f, 0.f, 0.f};

    int c0 = tid, c1 = tid + 256;               // chunk = 8 bf16; row=c>>2, kc=(c&3)*8
    const ushort* pa0 = &A[(size_t)(bm + (c0 >> 2)) * K + (c0 & 3) * 8];
    const ushort* pa1 = &A[(size_t)(bm + (c1 >> 2)) * K + (c1 & 3) * 8];
    const ushort* pb0 = &WT[(size_t)(bn + (c0 >> 2)) * K + (c0 & 3) * 8];
    const ushort* pb1 = &WT[(size_t)(bn + (c1 >> 2)) * K + (c1 & 3) * 8];

    for (int k0 = 0; k0 < K; k0 += 32) {
        short8 a0 = *(const short8*)(pa0 + k0);
        short8 a1 = *(const short8*)(pa1 + k0);
        short8 b0 = *(const short8*)(pb0 + k0);
        short8 b1 = *(const short8*)(pb1 + k0);
        __syncthreads();
        *(short8*)&As[c0 * 8] = a0;
        *(short8*)&As[c1 * 8] = a1;
        *(short8*)&Bs[c0 * 8] = b0;
        *(short8*)&Bs[c1 * 8] = b1;
        __syncthreads();

        short8 af[4], bw[4];
#pragma unroll
        for (int mt = 0; mt < 4; ++mt)
            af[mt] = *(const short8*)&As[(wm + mt * 16 + lm) * 32 + q8];
#pragma unroll
        for (int nt = 0; nt < 4; ++nt)
            bw[nt] = *(const short8*)&Bs[(wn + nt * 16 + lm) * 32 + q8];
#pragma unroll
        for (int mt = 0; mt < 4; ++mt)
#pragma unroll
            for (int nt = 0; nt < 4; ++nt)
                acc[mt][nt] = __builtin_amdgcn_mfma_f32_16x16x32_bf16(
                    af[mt], bw[nt], acc[mt][nt], 0, 0, 0);
    }

#pragma unroll
    for (int nt = 0; nt < 4; ++nt) {
        int col = bn + wn + nt * 16 + lm;
        float bv = bias[col];
#pragma unroll
        for (int mt = 0; mt < 4; ++mt) {
            int rowb = bm + wm + mt * 16 + (q8 >> 1);   // quad*4
#pragma unroll
            for (int r = 0; r < 4; ++r) {
                int row = rowb + r;
                float v = acc[mt][nt][r] + bv;
                if (GELU) v = 0.5f * v * (1.0f + erff(v * 0.70710678118654752f));
                if (RES) v += res[(size_t)row * N + col];
                if (OUTBF16)
                    ((__hip_bfloat16*)Cout)[(size_t)row * N + col] = __float2bfloat16(v);
                else
                    ((float*)Cout)[(size_t)row * N + col] = v;
            }
        }
    }
}

// ---------------- flash attention (bf16 in, bf16 out) ----------------
// qkv: [SEQ, 3*DIM] bf16; o: [SEQ, DIM] bf16 head-major.
// Block 256 thr: tq=tid>>4 owns rows {2tq,2tq+1}; tk=tid&15 (4 keys / 4 dims).
// 32-row Q tile, 64-key K/V tiles. LDS 49.4 KB -> 3 blocks/CU.

__device__ __forceinline__ float4 lds_r4(const float* buf, int r, int c4) {
    return *(const float4*)&buf[r * 64 + 4 * (c4 ^ ((r >> 2) & 7))];
}
__device__ __forceinline__ void lds_w4(float* buf, int r, int c4, float4 v) {
    *(float4*)&buf[r * 64 + 4 * (c4 ^ ((r >> 2) & 7))] = v;
}
__device__ __forceinline__ void unpack8(const ushort* p, float4& a, float4& b,
                                        float s) {
    uint4 u = *(const uint4*)p;
    a.x = __uint_as_float(u.x << 16) * s;
    a.y = __uint_as_float(u.x & 0xffff0000u) * s;
    a.z = __uint_as_float(u.y << 16) * s;
    a.w = __uint_as_float(u.y & 0xffff0000u) * s;
    b.x = __uint_as_float(u.z << 16) * s;
    b.y = __uint_as_float(u.z & 0xffff0000u) * s;
    b.z = __uint_as_float(u.w << 16) * s;
    b.w = __uint_as_float(u.w & 0xffff0000u) * s;
}

__global__ __launch_bounds__(256) void flash_attn_kernel(
        const ushort* __restrict__ qkv, __hip_bfloat16* __restrict__ o) {
    int qt = gridDim.x - 1 - blockIdx.x;   // heavy tiles first
    int head = blockIdx.y;
    int tid = threadIdx.x;
    int tq = tid >> 4, tk = tid & 15;

    __shared__ float Qs[32 * 64];
    __shared__ float Ks[64 * 64];
    __shared__ float Vs[64 * 64];
    __shared__ float Ps[32 * 68];

    {   // stage Q tile, scaled by 1/sqrt(64)
        int r = tid >> 3, c8 = tid & 7;
        float4 a, b;
        unpack8(&qkv[(size_t)(qt * 32 + r) * QKVD + head * HD + c8 * 8], a, b, 0.125f);
        lds_w4(Qs, r, c8 * 2, a);
        lds_w4(Qs, r, c8 * 2 + 1, b);
    }

    float m_i[2] = {-1e30f, -1e30f}, l_i[2] = {0.f, 0.f};
    float o_acc[2][4] = {};

    int kt_max = qt >> 1;
    for (int kt = 0; kt <= kt_max; ++kt) {
        __syncthreads();   // protect Ks/Vs (prev PV) and Qs (first iter)
#pragma unroll
        for (int ii = 0; ii < 2; ++ii) {
            int c = ii * 256 + tid;
            int r = c >> 3, c8 = c & 7;
            const ushort* kp = &qkv[(size_t)(kt * 64 + r) * QKVD + DIM + head * HD + c8 * 8];
            float4 a, b;
            unpack8(kp, a, b, 1.f);
            lds_w4(Ks, r, c8 * 2, a); lds_w4(Ks, r, c8 * 2 + 1, b);
            unpack8(kp + DIM, a, b, 1.f);
            lds_w4(Vs, r, c8 * 2, a); lds_w4(Vs, r, c8 * 2 + 1, b);
        }
        __syncthreads();

        // ---- scores S[2][4] ----
        float acc[2][4] = {};
#pragma unroll 4
        for (int c4 = 0; c4 < 16; ++c4) {
            float4 q0 = lds_r4(Qs, 2 * tq, c4);
            float4 q1 = lds_r4(Qs, 2 * tq + 1, c4);
#pragma unroll
            for (int j = 0; j < 4; ++j) {
                float4 kv = lds_r4(Ks, 4 * tk + j, c4);
                acc[0][j] += q0.x * kv.x + q0.y * kv.y + q0.z * kv.z + q0.w * kv.w;
                acc[1][j] += q1.x * kv.x + q1.y * kv.y + q1.z * kv.z + q1.w * kv.w;
            }
        }
        if (kt == kt_max) {   // causal mask (only tile that can cross diagonal)
#pragma unroll
            for (int i = 0; i < 2; ++i) {
                int rowg = qt * 32 + 2 * tq + i;
#pragma unroll
                for (int j = 0; j < 4; ++j)
                    if (kt * 64 + 4 * tk + j > rowg) acc[i][j] = -1e30f;
            }
        }

        // ---- online softmax (16-lane row groups) ----
#pragma unroll
        for (int i = 0; i < 2; ++i) {
            float tmax = fmaxf(fmaxf(acc[i][0], acc[i][1]),
                               fmaxf(acc[i][2], acc[i][3]));
            tmax = fmaxf(tmax, __shfl_xor(tmax, 1));
            tmax = fmaxf(tmax, __shfl_xor(tmax, 2));
            tmax = fmaxf(tmax, __shfl_xor(tmax, 4));
            tmax = fmaxf(tmax, __shfl_xor(tmax, 8));
            float m_new = fmaxf(m_i[i], tmax);
            float alpha = __expf(m_i[i] - m_new);
            m_i[i] = m_new;
            float p0 = __expf(acc[i][0] - m_new);
            float p1 = __expf(acc[i][1] - m_new);
            float p2 = __expf(acc[i][2] - m_new);
            float p3 = __expf(acc[i][3] - m_new);
            float ts = p0 + p1 + p2 + p3;
            ts += __shfl_xor(ts, 1);
            ts += __shfl_xor(ts, 2);
            ts += __shfl_xor(ts, 4);
            ts += __shfl_xor(ts, 8);
            l_i[i] = l_i[i] * alpha + ts;
            float* pr = &Ps[(2 * tq + i) * 68 + 4 * tk];
            pr[0] = p0; pr[1] = p1; pr[2] = p2; pr[3] = p3;
#pragma unroll
            for (int j = 0; j < 4; ++j) o_acc[i][j] *= alpha;
        }
        __syncthreads();

        // ---- PV: O[2][4] += P.V (tk = dim chunk) ----
#pragma unroll 4
        for (int kk4 = 0; kk4 < 16; ++kk4) {
            float4 p0 = *(const float4*)&Ps[(2 * tq) * 68 + kk4 * 4];
            float4 p1 = *(const float4*)&Ps[(2 * tq + 1) * 68 + kk4 * 4];
#pragma unroll
            for (int jj = 0; jj < 4; ++jj) {
                float4 vv = lds_r4(Vs, kk4 * 4 + jj, tk);
                float a0 = jj == 0 ? p0.x : jj == 1 ? p0.y : jj == 2 ? p0.z : p0.w;
                float a1 = jj == 0 ? p1.x : jj == 1 ? p1.y : jj == 2 ? p1.z : p1.w;
                o_acc[0][0] = fmaf(a0, vv.x, o_acc[0][0]);
                o_acc[0][1] = fmaf(a0, vv.y, o_acc[0][1]);
                o_acc[0][2] = fmaf(a0, vv.z, o_acc[0][2]);
                o_acc[0][3] = fmaf(a0, vv.w, o_acc[0][3]);
                o_acc[1][0] = fmaf(a1, vv.x, o_acc[1][0]);
                o_acc[1][1] = fmaf(a1, vv.y, o_acc[1][1]);
                o_acc[1][2] = fmaf(a1, vv.z, o_acc[1][2]);
                o_acc[1][3] = fmaf(a1, vv.w, o_acc[1][3]);
            }
        }
    }

#pragma unroll
    for (int i = 0; i < 2; ++i) {
        float inv = 1.0f / l_i[i];
        int row = qt * 32 + 2 * tq + i;
        __hip_bfloat16* op = &((__hip_bfloat16*)o)[(size_t)row * DIM + head * HD + tk * 4];
#pragma unroll
        for (int j = 0; j < 4; ++j) op[j] = __float2bfloat16(o_acc[i][j] * inv);
    }
}

extern "C" void kernel_launch(void* const* d_in, const int* in_sizes, int n_in,
                              void* d_out, int out_size, void* d_ws, size_t ws_size,
                              hipStream_t stream) {
    const int*   idx   = (const int*)  d_in[0];
    const float* emb   = (const float*)d_in[1];
    const float* pe    = (const float*)d_in[2];
    const float* qkv_w = (const float*)d_in[3];
    const float* qkv_b = (const float*)d_in[4];
    const float* out_w = (const float*)d_in[5];
    const float* out_b = (const float*)d_in[6];
    const float* ln1_s = (const float*)d_in[7];
    const float* ln1_b = (const float*)d_in[8];
    const float* ln2_s = (const float*)d_in[9];
    const float* ln2_b = (const float*)d_in[10];
    const float* w1    = (const float*)d_in[11];
    const float* b1    = (const float*)d_in[12];
    const float* w2    = (const float*)d_in[13];
    const float* b2    = (const float*)d_in[14];

    float* x = (float*)d_ws;                                   // [SEQ,DIM] f32
    __hip_bfloat16* h   = (__hip_bfloat16*)(x + SEQ * DIM);    // [SEQ,DIM] bf16 (also o)
    __hip_bfloat16* qkv = h + SEQ * DIM;                       // [SEQ,QKVD]
    __hip_bfloat16* ffa = qkv + (size_t)SEQ * QKVD;            // [SEQ,FFN]
    __hip_bfloat16* qkv_wT = ffa + (size_t)SEQ * FFN;          // [L,QKVD,DIM]
    __hip_bfloat16* out_wT = qkv_wT + (size_t)2 * QKVD * DIM;  // [L,DIM,DIM]
    __hip_bfloat16* w1T    = out_wT + (size_t)2 * DIM * DIM;   // [L,FFN,DIM]
    __hip_bfloat16* w2T    = w1T + (size_t)2 * FFN * DIM;      // [L,DIM,FFN]

    // weight prep (every call: d_ws is re-poisoned)
    transpose_w<<<dim3(QKVD / 32, DIM / 32, 2), 256, 0, stream>>>(qkv_w, qkv_wT, DIM, QKVD);
    transpose_w<<<dim3(DIM / 32, DIM / 32, 2), 256, 0, stream>>>(out_w, out_wT, DIM, DIM);
    transpose_w<<<dim3(FFN / 32, DIM / 32, 2), 256, 0, stream>>>(w1, w1T, DIM, FFN);
    transpose_w<<<dim3(DIM / 32, FFN / 32, 2), 256, 0, stream>>>(w2, w2T, FFN, DIM);

    embed_kernel<<<SEQ * DIM / 256, 256, 0, stream>>>(idx, emb, pe, x);

    for (int l = 0; l < 2; ++l) {
        ln_kernel<<<SEQ, 256, 0, stream>>>(x, ln1_s + l * DIM, ln1_b + l * DIM, h);
        mfma_gemm<false, false, true><<<dim3(QKVD / 128, SEQ / 128), 256, 0, stream>>>(
            (const ushort*)h, (const ushort*)(qkv_wT + (size_t)l * QKVD * DIM),
            qkv_b + l * QKVD, nullptr, qkv, SEQ, QKVD, DIM);
        flash_attn_kernel<<<dim3(SEQ / 32, NH), 256, 0, stream>>>(
            (const ushort*)qkv, h);   // o aliases h
        mfma_gemm<false, true, false><<<dim3(DIM / 128, SEQ / 128), 256, 0, stream>>>(
            (const ushort*)h, (const ushort*)(out_wT + (size_t)l * DIM * DIM),
            out_b + l * DIM, x, x, SEQ, DIM, DIM);
        ln_kernel<<<SEQ, 256, 0, stream>>>(x, ln2_s + l * DIM, ln2_b + l * DIM, h);
        mfma_gemm<true, false, true><<<dim3(FFN / 128, SEQ / 128), 256, 0, stream>>>(
            (const ushort*)h, (const ushort*)(w1T + (size_t)l * FFN * DIM),
            b1 + l * FFN, nullptr, ffa, SEQ, FFN, DIM);
        float* cdst = (l == 1) ? (float*)d_out : x;
        mfma_gemm<false, true, false><<<dim3(DIM / 128, SEQ / 128), 256, 0, stream>>>(
            (const ushort*)ffa, (const ushort*)(w2T + (size_t)l * DIM * FFN),
            b2 + l * DIM, x, cdst, SEQ, DIM, FFN);
    }
}

// Round 6
// 661.868 us; speedup vs baseline: 5.6636x; 1.6900x over previous
//
#include <hip/hip_runtime.h>
#include <hip/hip_bf16.h>

// TransformerShardA: 2-layer GPT-2 shard. B=1, S=2048, D=768, H=12, hd=64,
// FFN=3072. Inputs f32 (+int idx), output f32 [1,2048,768].
//
// Round 6: MFMA flash attention.
//  - S^T = K.Q^T via mfma_16x16x32_bf16 (C/D: key=quad*4+reg, qrow=lane&15)
//    -> softmax state is scalar-per-lane, reductions = shfl_xor 16/32.
//  - P written as [qrow][key] bf16 (1 ds_write_b64 per key-tile, per-wave
//    private buffer, stride 72 elem = conflict-free), PV as O^T = V^T.P^T.
//  - block = (head, pair qt<->31-qt): constant 33 key-tiles -> perfect balance,
//    grid 192 (1 block/CU). LDS 27.6 KB.
// GEMMs/LN unchanged from round 5.

#define SEQ 2048
#define DIM 768
#define NH 12
#define HD 64
#define FFN 3072
#define QKVD (3 * DIM)

typedef __attribute__((ext_vector_type(8))) short short8;
typedef __attribute__((ext_vector_type(4))) float f32x4;

__device__ __forceinline__ ushort bf16bits(float v) {
    __hip_bfloat16 hb = __float2bfloat16(v);
    return *reinterpret_cast<ushort*>(&hb);
}

// ---------------- embedding + positional ----------------
__global__ void embed_kernel(const int* __restrict__ idx,
                             const float* __restrict__ emb,
                             const float* __restrict__ pe,
                             float* __restrict__ x) {
    int i = blockIdx.x * 256 + threadIdx.x;
    int s = i / DIM;
    int d = i - s * DIM;
    x[i] = emb[idx[s] * DIM + d] + pe[i];
}

// ---------------- weight transpose + cast: W[K,N] f32 -> WT[N,K] bf16 -------
__global__ void transpose_w(const float* __restrict__ W,
                            __hip_bfloat16* __restrict__ WT, int K, int N) {
    __shared__ float t[32][33];
    const float* Wp = W + (size_t)blockIdx.z * K * N;
    __hip_bfloat16* Tp = WT + (size_t)blockIdx.z * K * N;
    int k0 = blockIdx.y * 32, n0 = blockIdx.x * 32;
    int r = threadIdx.x >> 3, c4 = (threadIdx.x & 7) * 4;
    float4 v = *(const float4*)&Wp[(size_t)(k0 + r) * N + n0 + c4];
    t[r][c4 + 0] = v.x; t[r][c4 + 1] = v.y; t[r][c4 + 2] = v.z; t[r][c4 + 3] = v.w;
    __syncthreads();
    __hip_bfloat16* dst = &Tp[(size_t)(n0 + r) * K + k0 + c4];
#pragma unroll
    for (int j = 0; j < 4; ++j) dst[j] = __float2bfloat16(t[c4 + j][r]);
}

// ---------------- LayerNorm (one block per row), writes bf16 ----------------
__global__ void ln_kernel(const float* __restrict__ x,
                          const float* __restrict__ sc,
                          const float* __restrict__ bi,
                          __hip_bfloat16* __restrict__ h) {
    int row = blockIdx.x, tid = threadIdx.x;
    __shared__ float red[256];
    const float* xr = x + row * DIM;
    float v[3];
#pragma unroll
    for (int i = 0; i < 3; ++i) v[i] = xr[tid + i * 256];
    float s = v[0] + v[1] + v[2];
    red[tid] = s; __syncthreads();
    for (int t = 128; t > 0; t >>= 1) {
        if (tid < t) red[tid] += red[tid + t];
        __syncthreads();
    }
    float mean = red[0] * (1.0f / DIM);
    __syncthreads();
    float q = 0.f;
#pragma unroll
    for (int i = 0; i < 3; ++i) { float d = v[i] - mean; q += d * d; }
    red[tid] = q; __syncthreads();
    for (int t = 128; t > 0; t >>= 1) {
        if (tid < t) red[tid] += red[tid + t];
        __syncthreads();
    }
    float rstd = rsqrtf(red[0] * (1.0f / DIM) + 1e-5f);
#pragma unroll
    for (int i = 0; i < 3; ++i) {
        int d = tid + i * 256;
        h[row * DIM + d] = __float2bfloat16((v[i] - mean) * rstd * sc[d] + bi[d]);
    }
}

// ---------------- bf16 MFMA GEMM: C = [res +] act(A@W + bias) ---------------
template <bool GELU, bool RES, bool OUTBF16>
__global__ __launch_bounds__(256) void mfma_gemm(
        const ushort* __restrict__ A, const ushort* __restrict__ WT,
        const float* __restrict__ bias, const float* __restrict__ res,
        void* __restrict__ Cout, int M, int N, int K) {
    __shared__ ushort As[128 * 32];
    __shared__ ushort Bs[128 * 32];
    int tid = threadIdx.x;
    int w = tid >> 6, lane = tid & 63;
    int wm = (w >> 1) * 64, wn = (w & 1) * 64;
    int bm = blockIdx.y * 128, bn = blockIdx.x * 128;
    int lm = lane & 15, q8 = (lane >> 4) * 8;

    f32x4 acc[4][4];
#pragma unroll
    for (int i = 0; i < 4; ++i)
#pragma unroll
        for (int j = 0; j < 4; ++j) acc[i][j] = {0.f, 0.f, 0.f, 0.f};

    int c0 = tid, c1 = tid + 256;
    const ushort* pa0 = &A[(size_t)(bm + (c0 >> 2)) * K + (c0 & 3) * 8];
    const ushort* pa1 = &A[(size_t)(bm + (c1 >> 2)) * K + (c1 & 3) * 8];
    const ushort* pb0 = &WT[(size_t)(bn + (c0 >> 2)) * K + (c0 & 3) * 8];
    const ushort* pb1 = &WT[(size_t)(bn + (c1 >> 2)) * K + (c1 & 3) * 8];

    for (int k0 = 0; k0 < K; k0 += 32) {
        short8 a0 = *(const short8*)(pa0 + k0);
        short8 a1 = *(const short8*)(pa1 + k0);
        short8 b0 = *(const short8*)(pb0 + k0);
        short8 b1 = *(const short8*)(pb1 + k0);
        __syncthreads();
        *(short8*)&As[c0 * 8] = a0;
        *(short8*)&As[c1 * 8] = a1;
        *(short8*)&Bs[c0 * 8] = b0;
        *(short8*)&Bs[c1 * 8] = b1;
        __syncthreads();

        short8 af[4], bw[4];
#pragma unroll
        for (int mt = 0; mt < 4; ++mt)
            af[mt] = *(const short8*)&As[(wm + mt * 16 + lm) * 32 + q8];
#pragma unroll
        for (int nt = 0; nt < 4; ++nt)
            bw[nt] = *(const short8*)&Bs[(wn + nt * 16 + lm) * 32 + q8];
#pragma unroll
        for (int mt = 0; mt < 4; ++mt)
#pragma unroll
            for (int nt = 0; nt < 4; ++nt)
                acc[mt][nt] = __builtin_amdgcn_mfma_f32_16x16x32_bf16(
                    af[mt], bw[nt], acc[mt][nt], 0, 0, 0);
    }

#pragma unroll
    for (int nt = 0; nt < 4; ++nt) {
        int col = bn + wn + nt * 16 + lm;
        float bv = bias[col];
#pragma unroll
        for (int mt = 0; mt < 4; ++mt) {
            int rowb = bm + wm + mt * 16 + (q8 >> 1);
#pragma unroll
            for (int r = 0; r < 4; ++r) {
                int row = rowb + r;
                float v = acc[mt][nt][r] + bv;
                if (GELU) v = 0.5f * v * (1.0f + erff(v * 0.70710678118654752f));
                if (RES) v += res[(size_t)row * N + col];
                if (OUTBF16)
                    ((__hip_bfloat16*)Cout)[(size_t)row * N + col] = __float2bfloat16(v);
                else
                    ((float*)Cout)[(size_t)row * N + col] = v;
            }
        }
    }
}

// ---------------- MFMA flash attention ----------------
// qkv: [SEQ, 3*DIM] bf16 (q/k/v at 0/DIM/2*DIM, inner [NH,HD]).
// o: [SEQ, DIM] bf16, head-major inner layout.
// Block = (pair, head): handles Q-tiles qt=pair and qt=31-pair (64 rows each)
// -> constant 33 K-tiles per block. 4 waves: wave w owns qrows w*16..w*16+15.
// S^T = K.Q^T: A-frag from Ks[key][dim], B-frag from Q[qrow][dim] (global).
// C/D: key=quad*4+reg, qrow=lane&15 -> per-lane scalar softmax state.
// P stored [qrow][key] bf16 per-wave (stride 72) -> B-frag for O^T = V^T.P^T.
__global__ __launch_bounds__(256) void flash_attn_kernel(
        const ushort* __restrict__ qkv, ushort* __restrict__ o) {
    int pair = blockIdx.x, head = blockIdx.y;
    int tid = threadIdx.x, w = tid >> 6, lane = tid & 63;
    int ln16 = lane & 15, quad = lane >> 4;

    __shared__ ushort Ks[64 * 72];      // [key][dim], pad 8
    __shared__ ushort Vt[64 * 72];      // [dim][key], pad 8
    __shared__ ushort Ps[4][16 * 72];   // per-wave [qrow][key], pad 8

#pragma unroll 1
    for (int ph = 0; ph < 2; ++ph) {
        int qt = ph ? (31 - pair) : pair;

        // Q B-frags (row-major [qrow][dim] -> operand1 = Q^T), reused all kt
        short8 qf[2];
        {
            const ushort* qp = &qkv[(size_t)(qt * 64 + w * 16 + ln16) * QKVD
                                    + head * HD + quad * 8];
            qf[0] = *(const short8*)qp;
            qf[1] = *(const short8*)(qp + 32);
        }

        float m_i = -1e30f, l_i = 0.f;
        f32x4 oacc[4];
#pragma unroll
        for (int mt = 0; mt < 4; ++mt) oacc[mt] = {0.f, 0.f, 0.f, 0.f};

        for (int kt = 0; kt <= qt; ++kt) {
            __syncthreads();   // prior PV done with Ks/Vt
            // ---- stage K (vectored) and V^T (scatter) ----
#pragma unroll
            for (int hh = 0; hh < 2; ++hh) {
                int t = hh * 256 + tid;
                int key = t >> 3, c8 = (t & 7) * 8;
                const ushort* kp = &qkv[(size_t)(kt * 64 + key) * QKVD + DIM
                                        + head * HD + c8];
                *(short8*)&Ks[key * 72 + c8] = *(const short8*)kp;
                short8 vv = *(const short8*)(kp + DIM);
#pragma unroll
                for (int j = 0; j < 8; ++j)
                    Vt[(c8 + j) * 72 + key] = ((const ushort*)&vv)[j];
            }
            __syncthreads();

            // ---- S^T = K.Q^T ----
            f32x4 s[4];
#pragma unroll
            for (int mt = 0; mt < 4; ++mt) {
                s[mt] = {0.f, 0.f, 0.f, 0.f};
#pragma unroll
                for (int kc = 0; kc < 2; ++kc) {
                    short8 kf = *(const short8*)&Ks[(mt * 16 + ln16) * 72
                                                    + kc * 32 + quad * 8];
                    s[mt] = __builtin_amdgcn_mfma_f32_16x16x32_bf16(
                        kf, qf[kc], s[mt], 0, 0, 0);
                }
            }

            // ---- scale + causal mask ----
            int qrow = qt * 64 + w * 16 + ln16;
            float sv[4][4];
#pragma unroll
            for (int mt = 0; mt < 4; ++mt)
#pragma unroll
                for (int r = 0; r < 4; ++r) {
                    float v = s[mt][r] * 0.125f;
                    int key = kt * 64 + mt * 16 + quad * 4 + r;
                    sv[mt][r] = (kt == qt && key > qrow) ? -1e30f : v;
                }

            // ---- online softmax (state per lane = per qrow) ----
            float tmax = -1e30f;
#pragma unroll
            for (int mt = 0; mt < 4; ++mt)
#pragma unroll
                for (int r = 0; r < 4; ++r) tmax = fmaxf(tmax, sv[mt][r]);
            tmax = fmaxf(tmax, __shfl_xor(tmax, 16));
            tmax = fmaxf(tmax, __shfl_xor(tmax, 32));
            float m_new = fmaxf(m_i, tmax);
            float alpha = __expf(m_i - m_new);
            m_i = m_new;

            float ls = 0.f;
#pragma unroll
            for (int mt = 0; mt < 4; ++mt) {
                union { ushort u[4]; unsigned long long ull; } pk;
#pragma unroll
                for (int r = 0; r < 4; ++r) {
                    float p = __expf(sv[mt][r] - m_new);
                    ls += p;
                    pk.u[r] = bf16bits(p);
                }
                *(unsigned long long*)&Ps[w][ln16 * 72 + mt * 16 + quad * 4] = pk.ull;
            }
            ls += __shfl_xor(ls, 16);
            ls += __shfl_xor(ls, 32);
            l_i = l_i * alpha + ls;

#pragma unroll
            for (int mt = 0; mt < 4; ++mt) {
                oacc[mt][0] *= alpha; oacc[mt][1] *= alpha;
                oacc[mt][2] *= alpha; oacc[mt][3] *= alpha;
            }

            // ---- O^T += V^T.P^T (P per-wave private: no barrier needed) ----
#pragma unroll
            for (int kc = 0; kc < 2; ++kc) {
                short8 pf = *(const short8*)&Ps[w][ln16 * 72 + kc * 32 + quad * 8];
#pragma unroll
                for (int mt = 0; mt < 4; ++mt) {
                    short8 vf = *(const short8*)&Vt[(mt * 16 + ln16) * 72
                                                    + kc * 32 + quad * 8];
                    oacc[mt] = __builtin_amdgcn_mfma_f32_16x16x32_bf16(
                        vf, pf, oacc[mt], 0, 0, 0);
                }
            }
        }

        // ---- epilogue: O^T[dim=quad*4+reg(+16mt)][qrow=ln16] ----
        float inv = 1.0f / l_i;
        int orow = qt * 64 + w * 16 + ln16;
#pragma unroll
        for (int mt = 0; mt < 4; ++mt)
#pragma unroll
            for (int r = 0; r < 4; ++r) {
                int dimc = head * HD + mt * 16 + quad * 4 + r;
                o[(size_t)orow * DIM + dimc] = bf16bits(oacc[mt][r] * inv);
            }
    }
}

extern "C" void kernel_launch(void* const* d_in, const int* in_sizes, int n_in,
                              void* d_out, int out_size, void* d_ws, size_t ws_size,
                              hipStream_t stream) {
    const int*   idx   = (const int*)  d_in[0];
    const float* emb   = (const float*)d_in[1];
    const float* pe    = (const float*)d_in[2];
    const float* qkv_w = (const float*)d_in[3];
    const float* qkv_b = (const float*)d_in[4];
    const float* out_w = (const float*)d_in[5];
    const float* out_b = (const float*)d_in[6];
    const float* ln1_s = (const float*)d_in[7];
    const float* ln1_b = (const float*)d_in[8];
    const float* ln2_s = (const float*)d_in[9];
    const float* ln2_b = (const float*)d_in[10];
    const float* w1    = (const float*)d_in[11];
    const float* b1    = (const float*)d_in[12];
    const float* w2    = (const float*)d_in[13];
    const float* b2    = (const float*)d_in[14];

    float* x = (float*)d_ws;                                   // [SEQ,DIM] f32
    __hip_bfloat16* h   = (__hip_bfloat16*)(x + SEQ * DIM);    // [SEQ,DIM] bf16 (also o)
    __hip_bfloat16* qkv = h + SEQ * DIM;                       // [SEQ,QKVD]
    __hip_bfloat16* ffa = qkv + (size_t)SEQ * QKVD;            // [SEQ,FFN]
    __hip_bfloat16* qkv_wT = ffa + (size_t)SEQ * FFN;          // [L,QKVD,DIM]
    __hip_bfloat16* out_wT = qkv_wT + (size_t)2 * QKVD * DIM;  // [L,DIM,DIM]
    __hip_bfloat16* w1T    = out_wT + (size_t)2 * DIM * DIM;   // [L,FFN,DIM]
    __hip_bfloat16* w2T    = w1T + (size_t)2 * FFN * DIM;      // [L,DIM,FFN]

    transpose_w<<<dim3(QKVD / 32, DIM / 32, 2), 256, 0, stream>>>(qkv_w, qkv_wT, DIM, QKVD);
    transpose_w<<<dim3(DIM / 32, DIM / 32, 2), 256, 0, stream>>>(out_w, out_wT, DIM, DIM);
    transpose_w<<<dim3(FFN / 32, DIM / 32, 2), 256, 0, stream>>>(w1, w1T, DIM, FFN);
    transpose_w<<<dim3(DIM / 32, FFN / 32, 2), 256, 0, stream>>>(w2, w2T, FFN, DIM);

    embed_kernel<<<SEQ * DIM / 256, 256, 0, stream>>>(idx, emb, pe, x);

    for (int l = 0; l < 2; ++l) {
        ln_kernel<<<SEQ, 256, 0, stream>>>(x, ln1_s + l * DIM, ln1_b + l * DIM, h);
        mfma_gemm<false, false, true><<<dim3(QKVD / 128, SEQ / 128), 256, 0, stream>>>(
            (const ushort*)h, (const ushort*)(qkv_wT + (size_t)l * QKVD * DIM),
            qkv_b + l * QKVD, nullptr, qkv, SEQ, QKVD, DIM);
        flash_attn_kernel<<<dim3(16, NH), 256, 0, stream>>>(
            (const ushort*)qkv, (ushort*)h);   // o aliases h
        mfma_gemm<false, true, false><<<dim3(DIM / 128, SEQ / 128), 256, 0, stream>>>(
            (const ushort*)h, (const ushort*)(out_wT + (size_t)l * DIM * DIM),
            out_b + l * DIM, x, x, SEQ, DIM, DIM);
        ln_kernel<<<SEQ, 256, 0, stream>>>(x, ln2_s + l * DIM, ln2_b + l * DIM, h);
        mfma_gemm<true, false, true><<<dim3(FFN / 128, SEQ / 128), 256, 0, stream>>>(
            (const ushort*)h, (const ushort*)(w1T + (size_t)l * FFN * DIM),
            b1 + l * FFN, nullptr, ffa, SEQ, FFN, DIM);
        float* cdst = (l == 1) ? (float*)d_out : x;
        mfma_gemm<false, true, false><<<dim3(DIM / 128, SEQ / 128), 256, 0, stream>>>(
            (const ushort*)ffa, (const ushort*)(w2T + (size_t)l * DIM * FFN),
            b2 + l * DIM, x, cdst, SEQ, DIM, FFN);
    }
}